// Round 11
// baseline (99.815 us; speedup 1.0000x reference)
//
#include <hip/hip_runtime.h>
#include <hip/hip_bf16.h>
#include <math.h>

#define NH 8
#define SDIM 9
#define NSEG 16
#define NATOM 512
#define NEDGE 8192
#define CIN 128
#define CHN 256
#define DH 32
#define FDIM 288            // SDIM*DH
#define EPS 1e-7f
#define SCALE 0.10206207261596577f   // sqrt(32/3)/32

typedef __attribute__((ext_vector_type(8))) short bf16x8;
typedef __attribute__((ext_vector_type(8))) short short8;
typedef __attribute__((ext_vector_type(4))) float f32x4;

// ---------------- helpers ----------------
__device__ inline float blockReduceMax(float v, float* red) {
    #pragma unroll
    for (int off = 32; off; off >>= 1) v = fmaxf(v, __shfl_xor(v, off, 64));
    int lane = threadIdx.x & 63, wid = threadIdx.x >> 6;
    if (lane == 0) red[wid] = v;
    __syncthreads();
    v = fmaxf(fmaxf(red[0], red[1]), fmaxf(red[2], red[3]));
    __syncthreads();
    return v;
}
__device__ inline int lower_bound_batch(const int* __restrict__ b, int val) {
    int lo = 0, hi = NEDGE;
    while (lo < hi) {
        int mid = (lo + hi) >> 1;
        if (b[mid] < val) lo = mid + 1; else hi = mid;
    }
    return lo;
}
__device__ inline ushort f2bu(float x) {
    __hip_bfloat16 b = __float2bfloat16(x);
    return *(ushort*)&b;
}

// ---------------- K0: transpose all weights to bf16 [l][o][c] ----------------
__global__ void __launch_bounds__(256) wtrans(const float* __restrict__ Wq, const float* __restrict__ Wk,
                                              const float* __restrict__ Wv, const float* __restrict__ Wo,
                                              ushort* __restrict__ WqT, ushort* __restrict__ WkT,
                                              ushort* __restrict__ WvT, ushort* __restrict__ WoT) {
    const int bid = blockIdx.x;
    const int tid = threadIdx.x;
    __shared__ float tile[64][33];
    const float* src; ushort* dst; int R, C, r0, c0;
    if (bid < 144) {
        const int z = bid / 48;
        const int rem = bid % 48;
        const int l = rem >> 4;
        const int t = rem & 15;
        R = CIN; C = CHN;
        r0 = (t >> 3) * 64; c0 = (t & 7) * 32;
        src = ((z == 0) ? Wq : (z == 1) ? Wk : Wv) + (size_t)l * R * C;
        dst = ((z == 0) ? WqT : (z == 1) ? WkT : WvT) + (size_t)l * R * C;
    } else {
        const int rem = bid - 144;
        const int l = rem >> 4;
        const int t = rem & 15;
        R = CHN; C = CIN;
        r0 = (t >> 2) * 64; c0 = (t & 3) * 32;
        src = Wo + (size_t)l * R * C;
        dst = WoT + (size_t)l * R * C;
    }
    #pragma unroll
    for (int p = 0; p < 8; ++p) {
        int row = p * 8 + (tid >> 5);
        int col = tid & 31;
        tile[row][col] = src[(size_t)(r0 + row) * C + c0 + col];
    }
    __syncthreads();
    #pragma unroll
    for (int p = 0; p < 8; ++p) {
        int c = p * 4 + (tid >> 6);
        int rr = tid & 63;
        dst[(size_t)(c0 + c) * R + r0 + rr] = f2bu(tile[rr][c]);
    }
}

// ---------------- K1: fused stage1: seg tables + MFMA qkv projections + stats zero ----------------
__global__ void __launch_bounds__(256) stage1(const int* __restrict__ batch,
                                              const int* __restrict__ am, const int* __restrict__ emap,
                                              const float* __restrict__ envelope,
                                              const float* __restrict__ attn_bias,
                                              float* __restrict__ E1, float* __restrict__ E2,
                                              const float* __restrict__ q, const float* __restrict__ k,
                                              const float* __restrict__ v,
                                              const ushort* __restrict__ WqT, const ushort* __restrict__ WkT,
                                              const ushort* __restrict__ WvT,
                                              const float* __restrict__ bq, const float* __restrict__ bk,
                                              const float* __restrict__ bv,
                                              ushort* __restrict__ qhB,
                                              ushort* __restrict__ khB,
                                              ushort* __restrict__ vhT,
                                              float* __restrict__ stats) {
    const int bid = blockIdx.x;
    const int tid = threadIdx.x;
    if (bid < NSEG * NH) {
        const int seg = bid & (NSEG - 1), h = bid >> 4;
        __shared__ float e1[NATOM];
        __shared__ float e2[NATOM];
        __shared__ float red[4];
        e1[tid] = 0.f; e1[tid + 256] = 0.f;
        e2[tid] = 0.f; e2[tid + 256] = 0.f;
        const float* bh = attn_bias + (size_t)h * NEDGE;
        float mv = -1e30f;
        for (int e = tid; e < NEDGE; e += 256) mv = fmaxf(mv, bh[e]);
        const float mb = blockReduceMax(mv, red);
        const int st = lower_bound_batch(batch, seg);
        const int en = lower_bound_batch(batch, seg + 1);
        for (int e = st + tid; e < en; e += 256) {
            int m = am[e], em = emap[e];
            float ev = envelope[em];
            float eb = __expf(bh[em] - mb);
            atomicAdd(&e1[m], ev * eb);
            atomicAdd(&e2[m], ev * ev * eb);
        }
        __syncthreads();
        size_t base = ((size_t)h * NSEG + seg) * NATOM;
        E1[base + tid] = e1[tid]; E1[base + tid + 256] = e1[tid + 256];
        E2[base + tid] = e2[tid]; E2[base + tid + 256] = e2[tid + 256];
        return;
    }
    if (bid < NSEG * NH + 432) {
        const int idx = bid - NSEG * NH;
        const int z = idx / 144;                 // 0:q 1:k 2:v
        const int rem = idx - z * 144;
        const int s = rem >> 4;                  // 0..8
        const int n0 = (rem & 15) * 32;
        const int l = (s == 0) ? 0 : ((s < 4) ? 1 : 2);
        const float* x = (z == 0) ? q : (z == 1) ? k : v;
        const ushort* WT = ((z == 0) ? WqT : (z == 1) ? WkT : WvT) + (size_t)l * CIN * CHN;
        const float* bias = (z == 0) ? bq : (z == 1) ? bk : bv;
        const int lane = tid & 63, w = tid >> 6;
        const int wr = w >> 1, wc = w & 1;
        const int r = lane & 15, kg = lane >> 4;
        const int arow = n0 + 16 * wr + r;
        const float* xrow = x + ((size_t)arow * SDIM + s) * CIN;
        f32x4 acc[8] = {};
        #pragma unroll
        for (int ks = 0; ks < 4; ++ks) {
            const int k0 = ks * 32 + kg * 8;
            float4 x0 = *(const float4*)(xrow + k0);
            float4 x1 = *(const float4*)(xrow + k0 + 4);
            bf16x8 a;
            a[0] = f2bu(x0.x); a[1] = f2bu(x0.y); a[2] = f2bu(x0.z); a[3] = f2bu(x0.w);
            a[4] = f2bu(x1.x); a[5] = f2bu(x1.y); a[6] = f2bu(x1.z); a[7] = f2bu(x1.w);
            #pragma unroll
            for (int j = 0; j < 8; ++j) {
                const int o = 128 * wc + 16 * j + r;
                bf16x8 bf = *(const bf16x8*)(WT + (size_t)o * CIN + k0);
                acc[j] = __builtin_amdgcn_mfma_f32_16x16x32_bf16(a, bf, acc[j], 0, 0, 0);
            }
        }
        const float sc = (z == 0) ? SCALE : 1.0f;
        #pragma unroll
        for (int j = 0; j < 8; ++j) {
            const int o = 128 * wc + 16 * j + r;
            const float bb = (s == 0) ? bias[o] : 0.f;
            const int h = o >> 5, dj = o & 31;
            const int f = s * DH + dj;
            if (z < 2) {
                ushort* dst = (z == 0) ? qhB : khB;
                #pragma unroll
                for (int p = 0; p < 4; ++p) {
                    int row = n0 + 16 * wr + kg * 4 + p;
                    dst[((size_t)h * NATOM + row) * FDIM + f] = f2bu((acc[j][p] + bb) * sc);
                }
            } else {
                ushort* dst = vhT + ((size_t)h * FDIM + f) * NATOM;
                #pragma unroll
                for (int p = 0; p < 4; ++p) {
                    int row = n0 + 16 * wr + kg * 4 + p;
                    dst[row] = f2bu(acc[j][p] + bb);
                }
            }
        }
        return;
    }
    {
        float4 z4 = {0.f, 0.f, 0.f, 0.f};
        float4* sp = (float4*)stats;
        sp[tid] = z4;
        sp[tid + 256] = z4;
    }
}

// ---------------- K2: fused scores GEMM + softmax + out GEMM + LN stats (8 waves) ----------------
// block = 16 rows of one head. Phase1 (R10-validated): scores+softmax -> sbuf[16][520] bf16.
// Phase2 (R9-validated math, 8-wave distribution): out = sbuf @ vhT, fp32 store + stat atomics.
#define SBST 520
__global__ void __launch_bounds__(512) attn_out_fused(const ushort* __restrict__ qhB,
                                                      const ushort* __restrict__ khB,
                                                      const ushort* __restrict__ vhT,
                                                      const float* __restrict__ E1,
                                                      const float* __restrict__ E2,
                                                      float* __restrict__ attnOut,
                                                      float* __restrict__ stats) {
    const int h = blockIdx.y;
    const int n0 = blockIdx.x * 16;
    __shared__ ushort sbuf[16 * SBST];     // 16.6 KB
    __shared__ float rowmax[8][16];
    __shared__ float Dpart[8][16][NSEG];   // 8 KB
    __shared__ float invDs[16][NSEG];
    const int tid = threadIdx.x;
    const int lane = tid & 63, w = tid >> 6;      // w: 0..7
    const int r = lane & 15, kg = lane >> 4;
    const ushort* A = qhB + (size_t)h * NATOM * FDIM;
    const ushort* B = khB + (size_t)h * NATOM * FDIM;
    const float* e1g = E1 + (size_t)h * NSEG * NATOM;
    const float* e2g = E2 + (size_t)h * NSEG * NATOM;
    const int ar = n0 + r;
    // ---- phase 1: scores GEMM, wave w owns cols [w*64, w*64+64) ----
    f32x4 acc[4] = {};
    #pragma unroll
    for (int ks = 0; ks < FDIM / 32; ++ks) {
        const int k0 = ks * 32 + kg * 8;
        bf16x8 a = *(const bf16x8*)(A + (size_t)ar * FDIM + k0);
        #pragma unroll
        for (int j = 0; j < 4; ++j) {
            const int bcol = w * 64 + 16 * j + r;
            bf16x8 b = *(const bf16x8*)(B + (size_t)bcol * FDIM + k0);
            acc[j] = __builtin_amdgcn_mfma_f32_16x16x32_bf16(a, b, acc[j], 0, 0, 0);
        }
    }
    // ---- row max ----
    float pm[4];
    #pragma unroll
    for (int p = 0; p < 4; ++p)
        pm[p] = fmaxf(fmaxf(acc[0][p], acc[1][p]), fmaxf(acc[2][p], acc[3][p]));
    #pragma unroll
    for (int mk = 1; mk < 16; mk <<= 1)
        #pragma unroll
        for (int p = 0; p < 4; ++p) pm[p] = fmaxf(pm[p], __shfl_xor(pm[p], mk, 64));
    if (r == 0) {
        #pragma unroll
        for (int p = 0; p < 4; ++p) rowmax[w][kg * 4 + p] = pm[p];
    }
    __syncthreads();
    float mx[4];
    #pragma unroll
    for (int p = 0; p < 4; ++p) {
        const int row = kg * 4 + p;
        float m = rowmax[0][row];
        #pragma unroll
        for (int ww2 = 1; ww2 < 8; ++ww2) m = fmaxf(m, rowmax[ww2][row]);
        mx[p] = m;
    }
    // ---- es ----
    float es[4][4];
    #pragma unroll
    for (int j = 0; j < 4; ++j)
        #pragma unroll
        for (int p = 0; p < 4; ++p) es[j][p] = __expf(acc[j][p] - mx[p]);
    // ---- D partials (E1 from L2) ----
    float Dp[4][NSEG] = {};
    #pragma unroll
    for (int j = 0; j < 4; ++j) {
        const int col = w * 64 + 16 * j + r;
        #pragma unroll
        for (int g = 0; g < NSEG; ++g) {
            float e1 = e1g[(size_t)g * NATOM + col];
            #pragma unroll
            for (int p = 0; p < 4; ++p) Dp[p][g] += es[j][p] * e1;
        }
    }
    #pragma unroll
    for (int mk = 1; mk < 16; mk <<= 1)
        #pragma unroll
        for (int p = 0; p < 4; ++p)
            #pragma unroll
            for (int g = 0; g < NSEG; ++g) Dp[p][g] += __shfl_xor(Dp[p][g], mk, 64);
    if (r == 0) {
        #pragma unroll
        for (int p = 0; p < 4; ++p)
            #pragma unroll
            for (int g = 0; g < NSEG; ++g) Dpart[w][kg * 4 + p][g] = Dp[p][g];
    }
    __syncthreads();
    if (tid < 256) {
        const int row = tid >> 4, g = tid & 15;
        float d = 0.f;
        #pragma unroll
        for (int ww2 = 0; ww2 < 8; ++ww2) d += Dpart[ww2][row][g];
        invDs[row][g] = 1.0f / (d + 1e-30f);
    }
    __syncthreads();
    // ---- attn weights -> sbuf ----
    float iv[4][NSEG];
    #pragma unroll
    for (int p = 0; p < 4; ++p)
        #pragma unroll
        for (int g = 0; g < NSEG; ++g) iv[p][g] = invDs[kg * 4 + p][g];
    #pragma unroll
    for (int j = 0; j < 4; ++j) {
        const int col = w * 64 + 16 * j + r;
        float ww[4] = {};
        #pragma unroll
        for (int g = 0; g < NSEG; ++g) {
            float e2 = e2g[(size_t)g * NATOM + col];
            #pragma unroll
            for (int p = 0; p < 4; ++p) ww[p] += e2 * iv[p][g];
        }
        #pragma unroll
        for (int p = 0; p < 4; ++p)
            sbuf[(kg * 4 + p) * SBST + col] = f2bu(es[j][p] * ww[p]);
    }
    __syncthreads();
    // ---- phase 2: out = attn(16x512) @ vhT; 18 f-frags distributed over 8 waves ----
    const ushort* Bv = vhT + (size_t)h * FDIM * NATOM;
    float S0[4] = {}, Q0[4] = {}, Q1[4] = {}, Q2[4] = {};
    for (int fi = w; fi < FDIM / 16; fi += 8) {
        const int f0 = fi * 16;
        f32x4 oacc = {};
        #pragma unroll
        for (int ks = 0; ks < NATOM / 32; ++ks) {
            const int k0 = ks * 32 + kg * 8;
            bf16x8 a = *(const bf16x8*)(sbuf + r * SBST + k0);
            bf16x8 b = *(const bf16x8*)(Bv + (size_t)(f0 + r) * NATOM + k0);
            oacc = __builtin_amdgcn_mfma_f32_16x16x32_bf16(a, b, oacc, 0, 0, 0);
        }
        const int f = f0 + r;
        const int s = f >> 5, dj = f & 31;      // s uniform within frag
        #pragma unroll
        for (int p = 0; p < 4; ++p) {
            const int row = n0 + kg * 4 + p;
            float x = oacc[p];
            attnOut[((size_t)row * SDIM + s) * CHN + h * DH + dj] = x;
            if (s == 0) { S0[p] += x; Q0[p] += x * x; }
            else if (s < 4) Q1[p] += x * x;
            else Q2[p] += x * x;
        }
    }
    #pragma unroll
    for (int mk = 1; mk < 16; mk <<= 1)
        #pragma unroll
        for (int p = 0; p < 4; ++p) {
            S0[p] += __shfl_xor(S0[p], mk, 64);
            Q0[p] += __shfl_xor(Q0[p], mk, 64);
            Q1[p] += __shfl_xor(Q1[p], mk, 64);
            Q2[p] += __shfl_xor(Q2[p], mk, 64);
        }
    if (r == 0) {
        #pragma unroll
        for (int p = 0; p < 4; ++p) {
            const int row = n0 + kg * 4 + p;
            atomicAdd(&stats[row * 4 + 0], S0[p]);
            atomicAdd(&stats[row * 4 + 1], Q0[p]);
            atomicAdd(&stats[row * 4 + 2], Q1[p]);
            atomicAdd(&stats[row * 4 + 3], Q2[p]);
        }
    }
}

// ---------------- K3: final projection with fused layernorm ----------------
__global__ void __launch_bounds__(256) so3out_ln(const float* __restrict__ attnOut,
                                                 const float* __restrict__ stats,
                                                 const float* __restrict__ gamma,
                                                 const float* __restrict__ beta,
                                                 const ushort* __restrict__ WoT,
                                                 const float* __restrict__ bo,
                                                 float* __restrict__ out) {
    const int s = blockIdx.y;
    const int n0 = blockIdx.x * 16;
    const int l = (s == 0) ? 0 : ((s < 4) ? 1 : 2);
    const int tid = threadIdx.x;
    const int lane = tid & 63, w = tid >> 6;
    const int r = lane & 15, kg = lane >> 4;
    const int ar = n0 + r;
    float mu, ivl;
    {
        float s0 = stats[ar * 4 + 0];
        float q0 = stats[ar * 4 + 1];
        float q1 = stats[ar * 4 + 2];
        float q2 = stats[ar * 4 + 3];
        float m0 = s0 * (1.0f / CHN);
        float var = q0 * (1.0f / CHN) - m0 * m0;
        if (s == 0) { mu = m0; ivl = 1.0f / sqrtf(var + EPS); }
        else if (s < 4) { mu = 0.f; ivl = 1.0f / sqrtf(q1 * (1.0f / (3 * CHN)) + EPS); }
        else { mu = 0.f; ivl = 1.0f / sqrtf(q2 * (1.0f / (5 * CHN)) + EPS); }
    }
    const float* xrow = attnOut + ((size_t)ar * SDIM + s) * CHN;
    const float* gl = gamma + l * CHN;
    const ushort* B = WoT + (size_t)l * CIN * CHN;
    f32x4 acc[2] = {};
    #pragma unroll
    for (int ks = 0; ks < CHN / 32; ++ks) {
        const int k0 = ks * 32 + kg * 8;
        float4 x0 = *(const float4*)(xrow + k0);
        float4 x1 = *(const float4*)(xrow + k0 + 4);
        float4 g0 = *(const float4*)(gl + k0);
        float4 g1 = *(const float4*)(gl + k0 + 4);
        float y[8];
        y[0] = (x0.x - mu) * ivl * g0.x; y[1] = (x0.y - mu) * ivl * g0.y;
        y[2] = (x0.z - mu) * ivl * g0.z; y[3] = (x0.w - mu) * ivl * g0.w;
        y[4] = (x1.x - mu) * ivl * g1.x; y[5] = (x1.y - mu) * ivl * g1.y;
        y[6] = (x1.z - mu) * ivl * g1.z; y[7] = (x1.w - mu) * ivl * g1.w;
        if (s == 0) {
            float4 b0 = *(const float4*)(beta + k0);
            float4 b1 = *(const float4*)(beta + k0 + 4);
            y[0] += b0.x; y[1] += b0.y; y[2] += b0.z; y[3] += b0.w;
            y[4] += b1.x; y[5] += b1.y; y[6] += b1.z; y[7] += b1.w;
        }
        bf16x8 a;
        #pragma unroll
        for (int jj = 0; jj < 8; ++jj) a[jj] = f2bu(y[jj]);
        bf16x8 b0f = *(const bf16x8*)(B + (size_t)(32 * w + r) * CHN + k0);
        bf16x8 b1f = *(const bf16x8*)(B + (size_t)(32 * w + 16 + r) * CHN + k0);
        acc[0] = __builtin_amdgcn_mfma_f32_16x16x32_bf16(a, b0f, acc[0], 0, 0, 0);
        acc[1] = __builtin_amdgcn_mfma_f32_16x16x32_bf16(a, b1f, acc[1], 0, 0, 0);
    }
    #pragma unroll
    for (int j = 0; j < 2; ++j) {
        const int o = 32 * w + 16 * j + r;
        const float badd = (s == 0) ? bo[o] : 0.f;
        #pragma unroll
        for (int p = 0; p < 4; ++p) {
            const int n = n0 + kg * 4 + p;
            out[((size_t)n * SDIM + s) * CIN + o] = acc[j][p] + badd;
        }
    }
}

extern "C" void kernel_launch(void* const* d_in, const int* in_sizes, int n_in,
                              void* d_out, int out_size, void* d_ws, size_t ws_size,
                              hipStream_t stream) {
    const float* q = (const float*)d_in[0];
    const float* k = (const float*)d_in[1];
    const float* v = (const float*)d_in[2];
    const float* envelope = (const float*)d_in[3];
    const float* attn_bias = (const float*)d_in[4];
    const int* atom_index = (const int*)d_in[5];
    const int* batch_index = (const int*)d_in[6];
    const int* edge_map = (const int*)d_in[7];
    const float* Wq = (const float*)d_in[8];
    const float* bq = (const float*)d_in[9];
    const float* Wk = (const float*)d_in[10];
    const float* bk = (const float*)d_in[11];
    const float* Wv = (const float*)d_in[12];
    const float* bv = (const float*)d_in[13];
    const float* gamma = (const float*)d_in[14];
    const float* beta = (const float*)d_in[15];
    const float* Wo = (const float*)d_in[16];
    const float* bo = (const float*)d_in[17];
    float* out = (float*)d_out;

    const size_t SZ_HNF = (size_t)NH * NATOM * FDIM;      // 1,179,648
    const size_t SZ_TAB = (size_t)NH * NSEG * NATOM;      // 65,536
    const size_t SZ_WOT = (size_t)3 * CIN * CHN;          // 98,304
    const size_t SZ_NSC = (size_t)NATOM * SDIM * CHN;     // 1,179,648

    char* wsb = (char*)d_ws;
    ushort* qhB = (ushort*)wsb;
    ushort* khB = qhB + SZ_HNF;
    ushort* vhT = khB + SZ_HNF;                           // [h][f][n]
    float* attnOut = (float*)(vhT + SZ_HNF);              // [n][s][c] fp32
    float* E1 = attnOut + SZ_NSC;
    float* E2 = E1 + SZ_TAB;
    ushort* WqT = (ushort*)(E2 + SZ_TAB);
    ushort* WkT = WqT + SZ_WOT;
    ushort* WvT = WkT + SZ_WOT;
    ushort* WoT = WvT + SZ_WOT;
    float* stats = (float*)(WoT + SZ_WOT);                // [n][4]

    size_t needed = 2 * 3 * SZ_HNF + 4 * SZ_NSC + 4 * 2 * SZ_TAB
                  + 2 * 4 * SZ_WOT + 4 * NATOM * 4 + 256;
    if (ws_size < needed) return;

    wtrans<<<192, 256, 0, stream>>>(Wq, Wk, Wv, Wo, WqT, WkT, WvT, WoT);
    stage1<<<NSEG * NH + 432 + 1, 256, 0, stream>>>(
        batch_index, atom_index, edge_map, envelope, attn_bias, E1, E2,
        q, k, v, WqT, WkT, WvT, bq, bk, bv, qhB, khB, vhT, stats);
    attn_out_fused<<<dim3(NATOM / 16, NH), 512, 0, stream>>>(
        qhB, khB, vhT, E1, E2, attnOut, stats);
    so3out_ln<<<dim3(NATOM / 16, SDIM), 256, 0, stream>>>(
        attnOut, stats, gamma, beta, WoT, bo, out);
}

// Round 12
// 72.536 us; speedup vs baseline: 1.3761x; 1.3761x over previous
//
#include <hip/hip_runtime.h>
#include <hip/hip_bf16.h>
#include <math.h>

#define NH 8
#define SDIM 9
#define NSEG 16
#define NATOM 512
#define NEDGE 8192
#define CIN 128
#define CHN 256
#define DH 32
#define FDIM 288            // SDIM*DH
#define EPS 1e-7f
#define SCALE 0.10206207261596577f   // sqrt(32/3)/32

typedef __attribute__((ext_vector_type(8))) short bf16x8;
typedef __attribute__((ext_vector_type(8))) short short8;
typedef __attribute__((ext_vector_type(4))) float f32x4;

// ---------------- helpers ----------------
__device__ inline float blockReduceMax(float v, float* red) {
    #pragma unroll
    for (int off = 32; off; off >>= 1) v = fmaxf(v, __shfl_xor(v, off, 64));
    int lane = threadIdx.x & 63, wid = threadIdx.x >> 6;
    if (lane == 0) red[wid] = v;
    __syncthreads();
    v = fmaxf(fmaxf(red[0], red[1]), fmaxf(red[2], red[3]));
    __syncthreads();
    return v;
}
__device__ inline int lower_bound_batch(const int* __restrict__ b, int val) {
    int lo = 0, hi = NEDGE;
    while (lo < hi) {
        int mid = (lo + hi) >> 1;
        if (b[mid] < val) lo = mid + 1; else hi = mid;
    }
    return lo;
}
__device__ inline ushort f2bu(float x) {
    __hip_bfloat16 b = __float2bfloat16(x);
    return *(ushort*)&b;
}
__device__ inline float bu2f(ushort u) {
    unsigned int v = ((unsigned int)u) << 16;
    return *(float*)&v;
}

// ---------------- K1: fused stage1: seg tables + WoT + MFMA qkv projections + stats zero ----------------
// blocks [0,128): E1/E2 seg tables; [128,176): WoT; [176,608): qkv proj (scalar-W); 608: zero stats
__global__ void __launch_bounds__(256) stage1(const int* __restrict__ batch,
                                              const int* __restrict__ am, const int* __restrict__ emap,
                                              const float* __restrict__ envelope,
                                              const float* __restrict__ attn_bias,
                                              float* __restrict__ E1, float* __restrict__ E2,
                                              const float* __restrict__ q, const float* __restrict__ k,
                                              const float* __restrict__ v,
                                              const float* __restrict__ Wq, const float* __restrict__ Wk,
                                              const float* __restrict__ Wv,
                                              const float* __restrict__ bq, const float* __restrict__ bk,
                                              const float* __restrict__ bv,
                                              ushort* __restrict__ qhB,
                                              ushort* __restrict__ khB,
                                              ushort* __restrict__ vhT,
                                              const float* __restrict__ Wo,
                                              ushort* __restrict__ WoT,
                                              float* __restrict__ stats) {
    const int bid = blockIdx.x;
    const int tid = threadIdx.x;
    if (bid < NSEG * NH) {
        // ---- segment table part ----
        const int seg = bid & (NSEG - 1), h = bid >> 4;
        __shared__ float e1[NATOM];
        __shared__ float e2[NATOM];
        __shared__ float red[4];
        e1[tid] = 0.f; e1[tid + 256] = 0.f;
        e2[tid] = 0.f; e2[tid + 256] = 0.f;
        const float* bh = attn_bias + (size_t)h * NEDGE;
        float mv = -1e30f;
        for (int e = tid; e < NEDGE; e += 256) mv = fmaxf(mv, bh[e]);
        const float mb = blockReduceMax(mv, red);   // barrier inside covers e1/e2 init
        const int st = lower_bound_batch(batch, seg);
        const int en = lower_bound_batch(batch, seg + 1);
        for (int e = st + tid; e < en; e += 256) {
            int m = am[e], em = emap[e];
            float ev = envelope[em];
            float eb = __expf(bh[em] - mb);
            atomicAdd(&e1[m], ev * eb);
            atomicAdd(&e2[m], ev * ev * eb);
        }
        __syncthreads();
        size_t base = ((size_t)h * NSEG + seg) * NATOM;
        E1[base + tid] = e1[tid]; E1[base + tid + 256] = e1[tid + 256];
        E2[base + tid] = e2[tid]; E2[base + tid + 256] = e2[tid + 256];
        return;
    }
    if (bid < NSEG * NH + 48) {
        // ---- WoT transpose: WoT[l][o][c] = bf16(Wo[l][c][o]) ----
        const int t = bid - NSEG * NH;
        const int l = t / 16;
        const int cb = (t & 15) >> 2, ob = t & 3;
        const int c0 = cb * 64, o0 = ob * 32;
        __shared__ float tile[64][33];
        const float* src = Wo + (size_t)l * CHN * CIN;
        #pragma unroll
        for (int p = 0; p < 8; ++p) {
            int row = p * 8 + (tid >> 5);
            int col = tid & 31;
            tile[row][col] = src[(size_t)(c0 + row) * CIN + o0 + col];
        }
        __syncthreads();
        ushort* dst = WoT + (size_t)l * CIN * CHN;
        #pragma unroll
        for (int p = 0; p < 8; ++p) {
            int o = p * 4 + (tid >> 6);
            int c = tid & 63;
            dst[(size_t)(o0 + o) * CHN + c0 + c] = f2bu(tile[c][o]);
        }
        return;
    }
    if (bid < NSEG * NH + 48 + 432) {
        // ---- MFMA projection part: 32 rows x 256 cols, K=128 ----
        const int idx = bid - (NSEG * NH + 48);
        const int z = idx / 144;                 // 0:q 1:k 2:v
        const int rem = idx - z * 144;
        const int s = rem >> 4;                  // 0..8
        const int n0 = (rem & 15) * 32;
        const int l = (s == 0) ? 0 : ((s < 4) ? 1 : 2);
        const float* x = (z == 0) ? q : (z == 1) ? k : v;
        const float* W = ((z == 0) ? Wq : (z == 1) ? Wk : Wv) + (size_t)l * CIN * CHN;
        const float* bias = (z == 0) ? bq : (z == 1) ? bk : bv;
        const int lane = tid & 63, w = tid >> 6;
        const int wr = w >> 1, wc = w & 1;
        const int r = lane & 15, kg = lane >> 4;
        const int arow = n0 + 16 * wr + r;
        const float* xrow = x + ((size_t)arow * SDIM + s) * CIN;
        f32x4 acc[8] = {};
        #pragma unroll
        for (int ks = 0; ks < 4; ++ks) {
            const int k0 = ks * 32 + kg * 8;
            float4 x0 = *(const float4*)(xrow + k0);
            float4 x1 = *(const float4*)(xrow + k0 + 4);
            bf16x8 a;
            a[0] = f2bu(x0.x); a[1] = f2bu(x0.y); a[2] = f2bu(x0.z); a[3] = f2bu(x0.w);
            a[4] = f2bu(x1.x); a[5] = f2bu(x1.y); a[6] = f2bu(x1.z); a[7] = f2bu(x1.w);
            #pragma unroll
            for (int j = 0; j < 8; ++j) {
                const int o = 128 * wc + 16 * j + r;
                const float* wp = W + (size_t)k0 * CHN + o;
                bf16x8 bf;
                #pragma unroll
                for (int jj = 0; jj < 8; ++jj) bf[jj] = f2bu(wp[(size_t)jj * CHN]);
                acc[j] = __builtin_amdgcn_mfma_f32_16x16x32_bf16(a, bf, acc[j], 0, 0, 0);
            }
        }
        const float sc = (z == 0) ? SCALE : 1.0f;
        #pragma unroll
        for (int j = 0; j < 8; ++j) {
            const int o = 128 * wc + 16 * j + r;
            const float bb = (s == 0) ? bias[o] : 0.f;
            const int h = o >> 5, dj = o & 31;
            const int f = s * DH + dj;
            if (z < 2) {
                ushort* dst = (z == 0) ? qhB : khB;
                #pragma unroll
                for (int p = 0; p < 4; ++p) {
                    int row = n0 + 16 * wr + kg * 4 + p;
                    dst[((size_t)h * NATOM + row) * FDIM + f] = f2bu((acc[j][p] + bb) * sc);
                }
            } else {
                ushort* dst = vhT + ((size_t)h * FDIM + f) * NATOM;
                #pragma unroll
                for (int p = 0; p < 4; ++p) {
                    int row = n0 + 16 * wr + kg * 4 + p;
                    dst[row] = f2bu(acc[j][p] + bb);
                }
            }
        }
        return;
    }
    // ---- zero stats buffer: 512*4 floats ----
    {
        float4 z4 = {0.f, 0.f, 0.f, 0.f};
        float4* sp = (float4*)stats;
        sp[tid] = z4;
        sp[tid + 256] = z4;
    }
}

// ---------------- K2: fused scores GEMM + collapsed softmax -> bf16 attnB (8 waves) ----------------
// XCD-swizzled 1-D grid of 256: h = bid & 7 (8 heads -> 8 XCDs), n-block = bid >> 3.
// Each XCD's L2 holds exactly one head's qhB/khB (0.6 MB) -> L2-resident.
#define SBST 520
__global__ void __launch_bounds__(512) attn_fused(const ushort* __restrict__ qhB,
                                                  const ushort* __restrict__ khB,
                                                  const float* __restrict__ E1,
                                                  const float* __restrict__ E2,
                                                  ushort* __restrict__ attnB) {
    const int h = blockIdx.x & 7;
    const int n0 = (blockIdx.x >> 3) * 16;
    __shared__ ushort sbuf[16 * SBST];     // 16.6 KB
    __shared__ float rowmax[8][16];
    __shared__ float Dpart[8][16][NSEG];   // 8 KB
    __shared__ float invDs[16][NSEG];
    const int tid = threadIdx.x;
    const int lane = tid & 63, w = tid >> 6;      // w: 0..7
    const int r = lane & 15, kg = lane >> 4;
    const ushort* A = qhB + (size_t)h * NATOM * FDIM;
    const ushort* B = khB + (size_t)h * NATOM * FDIM;
    const float* e1g = E1 + (size_t)h * NSEG * NATOM;
    const float* e2g = E2 + (size_t)h * NSEG * NATOM;
    const int ar = n0 + r;
    // ---- scores GEMM: wave w owns cols [w*64, w*64+64) ----
    f32x4 acc[4] = {};
    #pragma unroll
    for (int ks = 0; ks < FDIM / 32; ++ks) {
        const int k0 = ks * 32 + kg * 8;
        bf16x8 a = *(const bf16x8*)(A + (size_t)ar * FDIM + k0);
        #pragma unroll
        for (int j = 0; j < 4; ++j) {
            const int bcol = w * 64 + 16 * j + r;
            bf16x8 b = *(const bf16x8*)(B + (size_t)bcol * FDIM + k0);
            acc[j] = __builtin_amdgcn_mfma_f32_16x16x32_bf16(a, b, acc[j], 0, 0, 0);
        }
    }
    // ---- row max ----
    float pm[4];
    #pragma unroll
    for (int p = 0; p < 4; ++p)
        pm[p] = fmaxf(fmaxf(acc[0][p], acc[1][p]), fmaxf(acc[2][p], acc[3][p]));
    #pragma unroll
    for (int mk = 1; mk < 16; mk <<= 1)
        #pragma unroll
        for (int p = 0; p < 4; ++p) pm[p] = fmaxf(pm[p], __shfl_xor(pm[p], mk, 64));
    if (r == 0) {
        #pragma unroll
        for (int p = 0; p < 4; ++p) rowmax[w][kg * 4 + p] = pm[p];
    }
    __syncthreads();
    float mx[4];
    #pragma unroll
    for (int p = 0; p < 4; ++p) {
        const int row = kg * 4 + p;
        float m = rowmax[0][row];
        #pragma unroll
        for (int ww2 = 1; ww2 < 8; ++ww2) m = fmaxf(m, rowmax[ww2][row]);
        mx[p] = m;
    }
    // ---- es ----
    float es[4][4];
    #pragma unroll
    for (int j = 0; j < 4; ++j)
        #pragma unroll
        for (int p = 0; p < 4; ++p) es[j][p] = __expf(acc[j][p] - mx[p]);
    // ---- D partials (E1 from L2) ----
    float Dp[4][NSEG] = {};
    #pragma unroll
    for (int j = 0; j < 4; ++j) {
        const int col = w * 64 + 16 * j + r;
        #pragma unroll
        for (int g = 0; g < NSEG; ++g) {
            float e1 = e1g[(size_t)g * NATOM + col];
            #pragma unroll
            for (int p = 0; p < 4; ++p) Dp[p][g] += es[j][p] * e1;
        }
    }
    #pragma unroll
    for (int mk = 1; mk < 16; mk <<= 1)
        #pragma unroll
        for (int p = 0; p < 4; ++p)
            #pragma unroll
            for (int g = 0; g < NSEG; ++g) Dp[p][g] += __shfl_xor(Dp[p][g], mk, 64);
    if (r == 0) {
        #pragma unroll
        for (int p = 0; p < 4; ++p)
            #pragma unroll
            for (int g = 0; g < NSEG; ++g) Dpart[w][kg * 4 + p][g] = Dp[p][g];
    }
    __syncthreads();
    if (tid < 256) {
        const int row = tid >> 4, g = tid & 15;
        float d = 0.f;
        #pragma unroll
        for (int ww2 = 0; ww2 < 8; ++ww2) d += Dpart[ww2][row][g];
        invDs[row][g] = 1.0f / (d + 1e-30f);
    }
    __syncthreads();
    // ---- attn weights -> sbuf ----
    float iv[4][NSEG];
    #pragma unroll
    for (int p = 0; p < 4; ++p)
        #pragma unroll
        for (int g = 0; g < NSEG; ++g) iv[p][g] = invDs[kg * 4 + p][g];
    #pragma unroll
    for (int j = 0; j < 4; ++j) {
        const int col = w * 64 + 16 * j + r;
        float ww[4] = {};
        #pragma unroll
        for (int g = 0; g < NSEG; ++g) {
            float e2 = e2g[(size_t)g * NATOM + col];
            #pragma unroll
            for (int p = 0; p < 4; ++p) ww[p] += e2 * iv[p][g];
        }
        #pragma unroll
        for (int p = 0; p < 4; ++p)
            sbuf[(kg * 4 + p) * SBST + col] = f2bu(es[j][p] * ww[p]);
    }
    __syncthreads();
    // ---- coalesced copy LDS -> attnB ----
    {
        ushort* dst = attnB + ((size_t)h * NATOM + n0) * NATOM;
        #pragma unroll
        for (int i = tid * 8; i < 16 * NATOM; i += 4096) {
            const int row = i >> 9, col = i & 511;
            *(short8*)(dst + (size_t)row * NATOM + col) = *(short8*)(sbuf + row * SBST + col);
        }
    }
}

// ---------------- K3: MFMA out GEMM (64-row, 32-col f tiles) + LN stat atomics; bf16 out ----------------
// XCD-swizzled 1-D grid of 576: h = bid & 7; rest = bid >> 3; fb = rest % 9; nb = rest / 9.
__global__ void __launch_bounds__(256) gemm_out_stats(const ushort* __restrict__ attnB,
                                                      const ushort* __restrict__ vhT,
                                                      ushort* __restrict__ attnOutB,
                                                      float* __restrict__ stats) {
    const int h = blockIdx.x & 7;
    const int rest = blockIdx.x >> 3;
    const int fb = rest % 9;            // == s
    const int n0 = (rest / 9) * 64;
    const int tid = threadIdx.x;
    const int lane = tid & 63, w = tid >> 6;
    const int r = lane & 15, kg = lane >> 4;
    const ushort* A = attnB + (size_t)h * NATOM * NATOM;
    const ushort* B = vhT + (size_t)h * FDIM * NATOM;
    const int ar = n0 + 16 * w + r;
    f32x4 acc[2] = {};
    #pragma unroll 4
    for (int ks = 0; ks < NATOM / 32; ++ks) {
        const int k0 = ks * 32 + kg * 8;
        bf16x8 a = *(const bf16x8*)(A + (size_t)ar * NATOM + k0);
        bf16x8 b0 = *(const bf16x8*)(B + (size_t)(32 * fb + r) * NATOM + k0);
        bf16x8 b1 = *(const bf16x8*)(B + (size_t)(32 * fb + 16 + r) * NATOM + k0);
        acc[0] = __builtin_amdgcn_mfma_f32_16x16x32_bf16(a, b0, acc[0], 0, 0, 0);
        acc[1] = __builtin_amdgcn_mfma_f32_16x16x32_bf16(a, b1, acc[1], 0, 0, 0);
    }
    float sA[4], sB[4];
    #pragma unroll
    for (int p = 0; p < 4; ++p) { sA[p] = 0.f; sB[p] = 0.f; }
    #pragma unroll
    for (int j = 0; j < 2; ++j) {
        const int dj = 16 * j + r;
        #pragma unroll
        for (int p = 0; p < 4; ++p) {
            const int row = n0 + 16 * w + kg * 4 + p;
            float x = acc[j][p];
            attnOutB[((size_t)row * SDIM + fb) * CHN + h * DH + dj] = f2bu(x);
            sA[p] += x;
            sB[p] += x * x;
        }
    }
    #pragma unroll
    for (int mk = 1; mk < 16; mk <<= 1)
        #pragma unroll
        for (int p = 0; p < 4; ++p) {
            sA[p] += __shfl_xor(sA[p], mk, 64);
            sB[p] += __shfl_xor(sB[p], mk, 64);
        }
    if (r == 0) {
        #pragma unroll
        for (int p = 0; p < 4; ++p) {
            const int row = n0 + 16 * w + kg * 4 + p;
            if (fb == 0) {
                atomicAdd(&stats[row * 4 + 0], sA[p]);
                atomicAdd(&stats[row * 4 + 1], sB[p]);
            } else if (fb < 4) {
                atomicAdd(&stats[row * 4 + 2], sB[p]);
            } else {
                atomicAdd(&stats[row * 4 + 3], sB[p]);
            }
        }
    }
}

// ---------------- K4: final projection with fused layernorm (bf16 A-load) ----------------
__global__ void __launch_bounds__(256) so3out_ln(const ushort* __restrict__ attnOutB,
                                                 const float* __restrict__ stats,
                                                 const float* __restrict__ gamma,
                                                 const float* __restrict__ beta,
                                                 const ushort* __restrict__ WoT,
                                                 const float* __restrict__ bo,
                                                 float* __restrict__ out) {
    const int s = blockIdx.y;
    const int n0 = blockIdx.x * 16;
    const int l = (s == 0) ? 0 : ((s < 4) ? 1 : 2);
    const int tid = threadIdx.x;
    const int lane = tid & 63, w = tid >> 6;
    const int r = lane & 15, kg = lane >> 4;
    const int ar = n0 + r;
    float mu, ivl;
    {
        float s0 = stats[ar * 4 + 0];
        float q0 = stats[ar * 4 + 1];
        float q1 = stats[ar * 4 + 2];
        float q2 = stats[ar * 4 + 3];
        float m0 = s0 * (1.0f / CHN);
        float var = q0 * (1.0f / CHN) - m0 * m0;
        if (s == 0) { mu = m0; ivl = 1.0f / sqrtf(var + EPS); }
        else if (s < 4) { mu = 0.f; ivl = 1.0f / sqrtf(q1 * (1.0f / (3 * CHN)) + EPS); }
        else { mu = 0.f; ivl = 1.0f / sqrtf(q2 * (1.0f / (5 * CHN)) + EPS); }
    }
    const ushort* xrow = attnOutB + ((size_t)ar * SDIM + s) * CHN;
    const float* gl = gamma + l * CHN;
    const ushort* B = WoT + (size_t)l * CIN * CHN;
    f32x4 acc[2] = {};
    #pragma unroll
    for (int ks = 0; ks < CHN / 32; ++ks) {
        const int k0 = ks * 32 + kg * 8;
        bf16x8 x8 = *(const bf16x8*)(xrow + k0);
        float4 g0 = *(const float4*)(gl + k0);
        float4 g1 = *(const float4*)(gl + k0 + 4);
        float y[8];
        y[0] = (bu2f((ushort)x8[0]) - mu) * ivl * g0.x;
        y[1] = (bu2f((ushort)x8[1]) - mu) * ivl * g0.y;
        y[2] = (bu2f((ushort)x8[2]) - mu) * ivl * g0.z;
        y[3] = (bu2f((ushort)x8[3]) - mu) * ivl * g0.w;
        y[4] = (bu2f((ushort)x8[4]) - mu) * ivl * g1.x;
        y[5] = (bu2f((ushort)x8[5]) - mu) * ivl * g1.y;
        y[6] = (bu2f((ushort)x8[6]) - mu) * ivl * g1.z;
        y[7] = (bu2f((ushort)x8[7]) - mu) * ivl * g1.w;
        if (s == 0) {
            float4 b0 = *(const float4*)(beta + k0);
            float4 b1 = *(const float4*)(beta + k0 + 4);
            y[0] += b0.x; y[1] += b0.y; y[2] += b0.z; y[3] += b0.w;
            y[4] += b1.x; y[5] += b1.y; y[6] += b1.z; y[7] += b1.w;
        }
        bf16x8 a;
        #pragma unroll
        for (int jj = 0; jj < 8; ++jj) a[jj] = f2bu(y[jj]);
        bf16x8 b0f = *(const bf16x8*)(B + (size_t)(32 * w + r) * CHN + k0);
        bf16x8 b1f = *(const bf16x8*)(B + (size_t)(32 * w + 16 + r) * CHN + k0);
        acc[0] = __builtin_amdgcn_mfma_f32_16x16x32_bf16(a, b0f, acc[0], 0, 0, 0);
        acc[1] = __builtin_amdgcn_mfma_f32_16x16x32_bf16(a, b1f, acc[1], 0, 0, 0);
    }
    #pragma unroll
    for (int j = 0; j < 2; ++j) {
        const int o = 32 * w + 16 * j + r;
        const float badd = (s == 0) ? bo[o] : 0.f;
        #pragma unroll
        for (int p = 0; p < 4; ++p) {
            const int n = n0 + kg * 4 + p;
            out[((size_t)n * SDIM + s) * CIN + o] = acc[j][p] + badd;
        }
    }
}

extern "C" void kernel_launch(void* const* d_in, const int* in_sizes, int n_in,
                              void* d_out, int out_size, void* d_ws, size_t ws_size,
                              hipStream_t stream) {
    const float* q = (const float*)d_in[0];
    const float* k = (const float*)d_in[1];
    const float* v = (const float*)d_in[2];
    const float* envelope = (const float*)d_in[3];
    const float* attn_bias = (const float*)d_in[4];
    const int* atom_index = (const int*)d_in[5];
    const int* batch_index = (const int*)d_in[6];
    const int* edge_map = (const int*)d_in[7];
    const float* Wq = (const float*)d_in[8];
    const float* bq = (const float*)d_in[9];
    const float* Wk = (const float*)d_in[10];
    const float* bk = (const float*)d_in[11];
    const float* Wv = (const float*)d_in[12];
    const float* bv = (const float*)d_in[13];
    const float* gamma = (const float*)d_in[14];
    const float* beta = (const float*)d_in[15];
    const float* Wo = (const float*)d_in[16];
    const float* bo = (const float*)d_in[17];
    float* out = (float*)d_out;

    const size_t SZ_HNF = (size_t)NH * NATOM * FDIM;      // 1,179,648
    const size_t SZ_HNN = (size_t)NH * NATOM * NATOM;     // 2,097,152
    const size_t SZ_TAB = (size_t)NH * NSEG * NATOM;      // 65,536
    const size_t SZ_WOT = (size_t)3 * CIN * CHN;          // 98,304
    const size_t SZ_NSC = (size_t)NATOM * SDIM * CHN;     // 1,179,648

    char* wsb = (char*)d_ws;
    ushort* qhB = (ushort*)wsb;
    ushort* khB = qhB + SZ_HNF;
    ushort* vhT = khB + SZ_HNF;                           // [h][f][n]
    ushort* attnB = vhT + SZ_HNF;                         // [h][n][m]
    ushort* attnOutB = attnB + SZ_HNN;                    // [n][s][c] bf16
    float* E1 = (float*)(attnOutB + SZ_NSC);
    float* E2 = E1 + SZ_TAB;
    ushort* WoT = (ushort*)(E2 + SZ_TAB);                 // [l][o][c]
    float* stats = (float*)(WoT + SZ_WOT);                // [n][4]

    size_t needed = 2 * (3 * SZ_HNF + SZ_HNN + SZ_NSC + SZ_WOT)
                  + 4 * 2 * SZ_TAB + 4 * NATOM * 4 + 256;
    if (ws_size < needed) return;

    stage1<<<NSEG * NH + 48 + 432 + 1, 256, 0, stream>>>(
        batch_index, atom_index, edge_map, envelope, attn_bias, E1, E2,
        q, k, v, Wq, Wk, Wv, bq, bk, bv, qhB, khB, vhT, Wo, WoT, stats);
    attn_fused<<<NATOM / 16 * NH, 512, 0, stream>>>(qhB, khB, E1, E2, attnB);
    gemm_out_stats<<<SDIM * (NATOM / 64) * NH, 256, 0, stream>>>(attnB, vhT, attnOutB, stats);
    so3out_ln<<<dim3(NATOM / 16, SDIM), 256, 0, stream>>>(
        attnOutB, stats, gamma, beta, WoT, bo, out);
}